// Round 17
// baseline (61.171 us; speedup 1.0000x reference)
//
#include <hip/hip_runtime.h>
#include <hip/hip_fp16.h>

#define BB 2
#define NN 1024
#define MM 1024
#define DD 256
#define HH 128
#define C2LE 2.8853900817779268f       // 2*log2(e)
#define NEG2LOG2E -2.8853900817779268f // -2*log2(e)
#define SHIFT_C -4.3280860f            // -3*log2(e): P = e^{s-3}, softmax-invariant

typedef float v2f __attribute__((ext_vector_type(2)));
typedef float v4f __attribute__((ext_vector_type(4)));
typedef _Float16 h8 __attribute__((ext_vector_type(8)));

// ---- Kernel 1: blocks <512: e = exp2(C*(x@W+bias)) -> EaT (A, transposed) /
// Eb (B, row-major). blocks >=512: KT_hi[b][d][m] = f16(key^T).
__global__ __launch_bounds__(256) void proj_conv_kernel(
    const float* __restrict__ query, const float* __restrict__ key,
    const float* __restrict__ Wa_w, const float* __restrict__ Wa_b,
    const float* __restrict__ Wb_w, const float* __restrict__ Wb_b,
    float* __restrict__ EaT, float* __restrict__ Eb,
    __half* __restrict__ KT_hi) {
    __shared__ float rows[8][DD];
    __shared__ float partial[8][HH];
    __shared__ float t[64][65];
    const int tid = threadIdx.x;

    if (blockIdx.x >= 512) {  // ---- convert branch
        const int cid = blockIdx.x - 512;
        const int m0 = (cid & 15) * 64, d0 = ((cid >> 4) & 3) * 64, b = cid >> 6;
        for (int i = tid; i < 1024; i += 256) {
            const int r = i >> 4, c4 = i & 15;
            const float4 v =
                *(const float4*)&key[((size_t)(b * MM + m0 + r)) * DD + d0 + c4 * 4];
            t[r][c4 * 4 + 0] = v.x; t[r][c4 * 4 + 1] = v.y;
            t[r][c4 * 4 + 2] = v.z; t[r][c4 * 4 + 3] = v.w;
        }
        __syncthreads();
        for (int i = tid; i < 4096; i += 256) {
            const int dr = i >> 6, mc = i & 63;
            KT_hi[((size_t)(b * DD + d0 + dr)) * MM + m0 + mc] =
                __float2half(t[mc][dr]);
        }
        return;
    }

    const int rb = blockIdx.x * 8;
    const bool isA = rb < BB * NN;
    const float* in = isA ? query : key;
    const float* W  = isA ? Wa_w : Wb_w;
    const float* bias = isA ? Wa_b : Wb_b;
    const int base = isA ? rb : rb - BB * NN;

    const float4* in4 = (const float4*)(in + (size_t)base * DD);
    float4* rows4 = (float4*)rows;
    rows4[tid] = in4[tid];
    rows4[tid + 256] = in4[tid + 256];
    __syncthreads();

    const int h = tid & 127, half = tid >> 7;
    const int d0 = half * 128;
    float acc[8] = {};
    for (int d = d0; d < d0 + 128; d += 4) {
        const float w0 = W[(d + 0) * HH + h];
        const float w1 = W[(d + 1) * HH + h];
        const float w2 = W[(d + 2) * HH + h];
        const float w3 = W[(d + 3) * HH + h];
#pragma unroll
        for (int r = 0; r < 8; ++r) {
            const float4 rv = *(const float4*)&rows[r][d];
            acc[r] = fmaf(rv.x, w0, fmaf(rv.y, w1, fmaf(rv.z, w2, fmaf(rv.w, w3, acc[r]))));
        }
    }
    if (half) {
#pragma unroll
        for (int r = 0; r < 8; ++r) partial[r][h] = acc[r];
    }
    __syncthreads();
    if (!half) {
        const float bv = bias[h];
        float ev[8];
#pragma unroll
        for (int r = 0; r < 8; ++r)
            ev[r] = __builtin_amdgcn_exp2f(C2LE * (acc[r] + partial[r][h] + bv));
        if (isA) {
            const int bq = base >> 10, nb = base & (NN - 1);
            float* dst = EaT + ((size_t)(bq * HH + h)) * NN + nb;
            *(float4*)dst = *(float4*)&ev[0];
            *(float4*)(dst + 4) = *(float4*)&ev[4];
        } else {
#pragma unroll
            for (int r = 0; r < 8; ++r)
                Eb[(size_t)(base + r) * HH + h] = ev[r];
        }
    }
}

// ---- Kernel 2 v3: Ph = f16(exp(-2*sum_h v_h/(Ea*Eb+1) - 3)) + psum.
// Tile 16n x 256m (mt=4 per lane), h in 2 chunks of 64. a-broadcast LDS
// reads amortized over 2x more m per wave (the measured bottleneck).
__global__ __launch_bounds__(256) void scores_kernel(
    const float* __restrict__ EaT, const float* __restrict__ Eb,
    const float* __restrict__ v_w, __half* __restrict__ Ph,
    float* __restrict__ psum) {
    __shared__ float b_s[256 * 64];  // 64KB, swizzled: slot = h4 ^ (r&15)
    __shared__ float a_s[64 * 16];   // 4KB, [h][n]
    const int tid = threadIdx.x;
    const int m0 = blockIdx.x * 256, n0 = blockIdx.y * 16, b = blockIdx.z;
    const int lane = tid & 63;
    const int ng = __builtin_amdgcn_readfirstlane(threadIdx.x >> 6);
    const int skey = lane & 15;

    v2f acc[4][2] = {};  // [mt][np]
    for (int hc = 0; hc < 2; ++hc) {
        __syncthreads();
        for (int i = tid; i < 256 * 16; i += 256) {
            const int r = i >> 4, h4 = i & 15;
            *(float4*)&b_s[r * 64 + ((h4 ^ (r & 15)) << 2)] =
                *(const float4*)&Eb[((size_t)(b * MM + m0 + r)) * HH + hc * 64 + h4 * 4];
        }
        {   // 256 float4s: one per thread
            const int hh = tid >> 2, n4 = tid & 3;
            *(float4*)&a_s[hh * 16 + n4 * 4] =
                *(const float4*)&EaT[((size_t)(b * HH + hc * 64 + hh)) * NN + n0 + n4 * 4];
        }
        __syncthreads();

#pragma unroll 4
        for (int h4 = 0; h4 < 16; ++h4) {
            const float4 w4 = *(const float4*)&v_w[hc * 64 + h4 * 4];  // uniform
            const float* ap = &a_s[h4 * 4 * 16 + ng * 4];
            v2f A0[2], A1[2], A2[2], A3[2];
#pragma unroll
            for (int np = 0; np < 2; ++np) {
                A0[np] = *(const v2f*)&ap[0 * 16 + np * 2];  // broadcasts
                A1[np] = *(const v2f*)&ap[1 * 16 + np * 2];
                A2[np] = *(const v2f*)&ap[2 * 16 + np * 2];
                A3[np] = *(const v2f*)&ap[3 * 16 + np * 2];
            }
#pragma unroll
            for (int mt = 0; mt < 4; ++mt) {
                const float4 b4 = *(const float4*)
                    &b_s[(mt * 64 + lane) * 64 + ((h4 ^ skey) << 2)];
#pragma unroll
                for (int np = 0; np < 2; ++np) {
                    const v2f u0 = A0[np] * b4.x + 1.0f;
                    const v2f u1 = A1[np] * b4.y + 1.0f;
                    const v2f u2 = A2[np] * b4.z + 1.0f;
                    const v2f u3 = A3[np] * b4.w + 1.0f;
                    const v2f p01 = u0 * u1, p23 = u2 * u3;
                    const v2f An = w4.x * u1 + w4.y * u0;
                    const v2f Bn = w4.z * u3 + w4.w * u2;
                    const v2f num = An * p23 + Bn * p01;
                    const v2f Pp = p01 * p23;
                    v2f r2;
                    r2.x = __builtin_amdgcn_rcpf(Pp.x);
                    r2.y = __builtin_amdgcn_rcpf(Pp.y);
                    acc[mt][np] = num * r2 + acc[mt][np];
                }
            }
        }
    }

    const size_t prow = ((size_t)b * NN + n0 + ng * 4) * MM + m0 + lane;
#pragma unroll
    for (int j = 0; j < 4; ++j) {
#pragma unroll
        for (int mt = 0; mt < 4; ++mt) {
            const float pv = __builtin_amdgcn_exp2f(
                fmaf(acc[mt][j >> 1][j & 1], NEG2LOG2E, SHIFT_C));
            Ph[prow + (size_t)j * MM + mt * 64] = __float2half(pv);
            float s = pv;
#pragma unroll
            for (int o = 32; o > 0; o >>= 1) s += __shfl_xor(s, o);
            if (lane == 0)
                psum[((size_t)(m0 / 64 + mt) * BB + b) * NN + n0 + ng * 4 + j] = s;
        }
    }
}

// ---- Kernel 3 v6: full-k LDS-staged MFMA GEMM, normalize fused, direct out.
__global__ __launch_bounds__(512) void attend_kernel(
    const __half* __restrict__ Ph, const __half* __restrict__ KT_hi,
    const float* __restrict__ psum, float* __restrict__ out) {
    __shared__ __align__(16) __half Ab[2][4 * 512];  // 4KB x2
    __shared__ __align__(16) __half Bb[2][8 * 512];  // 8KB x2
    __shared__ float inv[32];

    const int bid = blockIdx.x;
    const int g = bid & 7, nt = bid >> 3;
    const int dt = g >> 1, b = g & 1;
    const int n0 = nt * 32, d0 = dt * 64;

    const int tid = threadIdx.x;
    const int lane = tid & 63;
    const int row16 = lane & 15, kg = lane >> 4;

    if (tid < 32) {
        float s = 0.f;
#pragma unroll
        for (int q = 0; q < 16; ++q)
            s += psum[((size_t)q * BB + b) * NN + n0 + tid];
        inv[tid] = __builtin_amdgcn_rcpf(s);
    }

    const int cb = tid >> 6;
    const int sdB = cb >> 1, skhB = cb & 1;
    const __half* srcB = KT_hi +
        ((size_t)(b * DD + d0 + sdB * 16 + row16)) * MM + skhB * 32 + kg * 8;
    const bool hasA = tid < 256;
    const int ca = cb & 3;
    const int snA = ca >> 1, skhA = ca & 1;
    const __half* srcA = Ph +
        ((size_t)(b * NN + n0 + snA * 16 + row16)) * MM + skhA * 32 + kg * 8;

    const int wave = __builtin_amdgcn_readfirstlane(threadIdx.x >> 6);
    const int t = wave >> 2, td = wave & 3;

    v4f c = {0.f, 0.f, 0.f, 0.f};

    h8 rb = *(const h8*)srcB;
    h8 ra;
    if (hasA) ra = *(const h8*)srcA;

    int cur = 0;
#pragma unroll 1
    for (int step = 0; step < 16; ++step) {
        *(h8*)&Bb[cur][cb * 512 + lane * 8] = rb;
        if (hasA) *(h8*)&Ab[cur][ca * 512 + lane * 8] = ra;
        if (step < 15) {
            rb = *(const h8*)(srcB + (step + 1) * 64);
            if (hasA) ra = *(const h8*)(srcA + (step + 1) * 64);
        }
        asm volatile("s_waitcnt lgkmcnt(0)" ::: "memory");
        __builtin_amdgcn_sched_barrier(0);
        __builtin_amdgcn_s_barrier();  // raw barrier: no vmcnt(0) drain

        const h8 a0 = *(const h8*)&Ab[cur][(t * 2 + 0) * 512 + lane * 8];
        const h8 a1 = *(const h8*)&Ab[cur][(t * 2 + 1) * 512 + lane * 8];
        const h8 b0 = *(const h8*)&Bb[cur][(td * 2 + 0) * 512 + lane * 8];
        const h8 b1 = *(const h8*)&Bb[cur][(td * 2 + 1) * 512 + lane * 8];
        c = __builtin_amdgcn_mfma_f32_16x16x32_f16(a0, b0, c, 0, 0, 0);
        c = __builtin_amdgcn_mfma_f32_16x16x32_f16(a1, b1, c, 0, 0, 0);
        cur ^= 1;
    }

    const int nloc = t * 16 + kg * 4;
    float* po = out + ((size_t)(b * NN + n0 + nloc)) * DD + d0 + td * 16 + row16;
#pragma unroll
    for (int r = 0; r < 4; ++r)
        po[(size_t)r * DD] = c[r] * inv[nloc + r];
}

extern "C" void kernel_launch(void* const* d_in, const int* in_sizes, int n_in,
                              void* d_out, int out_size, void* d_ws, size_t ws_size,
                              hipStream_t stream) {
    const float* query = (const float*)d_in[0];
    const float* key   = (const float*)d_in[1];
    const float* Wa_w  = (const float*)d_in[2];
    const float* Wa_b  = (const float*)d_in[3];
    const float* Wb_w  = (const float*)d_in[4];
    const float* Wb_b  = (const float*)d_in[5];
    const float* v_w   = (const float*)d_in[6];
    float* out = (float*)d_out;

    float* ws = (float*)d_ws;
    float* EaT  = ws;                          // BB*HH*NN f32
    float* Eb   = EaT + BB * NN * HH;          // BB*MM*HH f32
    float* psum = Eb + BB * MM * HH;           // 16*BB*NN f32
    __half* Ph    = (__half*)(psum + 16 * BB * NN);   // BB*NN*MM f16
    __half* KT_hi = Ph + (size_t)BB * NN * MM;        // BB*DD*MM f16

    proj_conv_kernel<<<dim3(512 + 128), dim3(256), 0, stream>>>(
        query, key, Wa_w, Wa_b, Wb_w, Wb_b, EaT, Eb, KT_hi);
    scores_kernel<<<dim3(MM / 256, NN / 16, BB), dim3(256), 0, stream>>>(
        EaT, Eb, v_w, Ph, psum);
    attend_kernel<<<dim3(256), dim3(512), 0, stream>>>(
        Ph, KT_hi, psum, out);
}

// Round 18
// 54.094 us; speedup vs baseline: 1.1308x; 1.1308x over previous
//
#include <hip/hip_runtime.h>
#include <hip/hip_fp16.h>

#define BB 2
#define NN 1024
#define MM 1024
#define DD 256
#define HH 128
#define C2LE 2.8853900817779268f       // 2*log2(e)
#define NEG2LOG2E -2.8853900817779268f // -2*log2(e)
#define SHIFT_C -4.3280860f            // -3*log2(e): P = e^{s-3}, softmax-invariant

typedef float v2f __attribute__((ext_vector_type(2)));
typedef float v4f __attribute__((ext_vector_type(4)));
typedef _Float16 h8 __attribute__((ext_vector_type(8)));

// ---- Kernel 1: blocks <512: e = exp2(C*(x@W+bias)) -> EaT (A, transposed) /
// Eb (B, row-major). blocks >=512: KT_hi[b][d][m] = f16(key^T).
__global__ __launch_bounds__(256) void proj_conv_kernel(
    const float* __restrict__ query, const float* __restrict__ key,
    const float* __restrict__ Wa_w, const float* __restrict__ Wa_b,
    const float* __restrict__ Wb_w, const float* __restrict__ Wb_b,
    float* __restrict__ EaT, float* __restrict__ Eb,
    __half* __restrict__ KT_hi) {
    __shared__ float rows[8][DD];
    __shared__ float partial[8][HH];
    __shared__ float t[64][65];
    const int tid = threadIdx.x;

    if (blockIdx.x >= 512) {  // ---- convert branch
        const int cid = blockIdx.x - 512;
        const int m0 = (cid & 15) * 64, d0 = ((cid >> 4) & 3) * 64, b = cid >> 6;
        for (int i = tid; i < 1024; i += 256) {
            const int r = i >> 4, c4 = i & 15;
            const float4 v =
                *(const float4*)&key[((size_t)(b * MM + m0 + r)) * DD + d0 + c4 * 4];
            t[r][c4 * 4 + 0] = v.x; t[r][c4 * 4 + 1] = v.y;
            t[r][c4 * 4 + 2] = v.z; t[r][c4 * 4 + 3] = v.w;
        }
        __syncthreads();
        for (int i = tid; i < 4096; i += 256) {
            const int dr = i >> 6, mc = i & 63;
            KT_hi[((size_t)(b * DD + d0 + dr)) * MM + m0 + mc] =
                __float2half(t[mc][dr]);
        }
        return;
    }

    const int rb = blockIdx.x * 8;
    const bool isA = rb < BB * NN;
    const float* in = isA ? query : key;
    const float* W  = isA ? Wa_w : Wb_w;
    const float* bias = isA ? Wa_b : Wb_b;
    const int base = isA ? rb : rb - BB * NN;

    const float4* in4 = (const float4*)(in + (size_t)base * DD);
    float4* rows4 = (float4*)rows;
    rows4[tid] = in4[tid];
    rows4[tid + 256] = in4[tid + 256];
    __syncthreads();

    const int h = tid & 127, half = tid >> 7;
    const int d0 = half * 128;
    float acc[8] = {};
    for (int d = d0; d < d0 + 128; d += 4) {
        const float w0 = W[(d + 0) * HH + h];
        const float w1 = W[(d + 1) * HH + h];
        const float w2 = W[(d + 2) * HH + h];
        const float w3 = W[(d + 3) * HH + h];
#pragma unroll
        for (int r = 0; r < 8; ++r) {
            const float4 rv = *(const float4*)&rows[r][d];
            acc[r] = fmaf(rv.x, w0, fmaf(rv.y, w1, fmaf(rv.z, w2, fmaf(rv.w, w3, acc[r]))));
        }
    }
    if (half) {
#pragma unroll
        for (int r = 0; r < 8; ++r) partial[r][h] = acc[r];
    }
    __syncthreads();
    if (!half) {
        const float bv = bias[h];
        float ev[8];
#pragma unroll
        for (int r = 0; r < 8; ++r)
            ev[r] = __builtin_amdgcn_exp2f(C2LE * (acc[r] + partial[r][h] + bv));
        if (isA) {
            const int bq = base >> 10, nb = base & (NN - 1);
            float* dst = EaT + ((size_t)(bq * HH + h)) * NN + nb;
            *(float4*)dst = *(float4*)&ev[0];
            *(float4*)(dst + 4) = *(float4*)&ev[4];
        } else {
#pragma unroll
            for (int r = 0; r < 8; ++r)
                Eb[(size_t)(base + r) * HH + h] = ev[r];
        }
    }
}

// ---- Kernel 2 v4: same tile/inner-loop as v2 (32n x 128m, 40KB LDS) but
// 512 threads (8 waves, 4n each) -> 16 waves/CU (4/SIMD), 2x occupancy.
__global__ __launch_bounds__(512) void scores_kernel(
    const float* __restrict__ EaT, const float* __restrict__ Eb,
    const float* __restrict__ v_w, __half* __restrict__ Ph,
    float* __restrict__ psum) {
    __shared__ float b_s[128 * 64];  // 32KB, swizzled: slot = h4 ^ (r&15)
    __shared__ float a_s[64 * 32];   // 8KB, [h][n]
    const int tid = threadIdx.x;
    const int m0 = blockIdx.x * 128, n0 = blockIdx.y * 32, b = blockIdx.z;
    const int lane = tid & 63;
    const int ng = __builtin_amdgcn_readfirstlane(threadIdx.x >> 6);  // 0..7
    const int skey = lane & 15;

    v2f acc[2][2] = {};  // [mt][np]
    for (int hc = 0; hc < 2; ++hc) {
        __syncthreads();
        for (int i = tid; i < 128 * 16; i += 512) {
            const int r = i >> 4, h4 = i & 15;
            *(float4*)&b_s[r * 64 + ((h4 ^ (r & 15)) << 2)] =
                *(const float4*)&Eb[((size_t)(b * MM + m0 + r)) * HH + hc * 64 + h4 * 4];
        }
        for (int i = tid; i < 64 * 8; i += 512) {
            const int hh = i >> 3, n4 = i & 7;
            *(float4*)&a_s[hh * 32 + n4 * 4] =
                *(const float4*)&EaT[((size_t)(b * HH + hc * 64 + hh)) * NN + n0 + n4 * 4];
        }
        __syncthreads();

#pragma unroll 4
        for (int h4 = 0; h4 < 16; ++h4) {
            const float4 w4 = *(const float4*)&v_w[hc * 64 + h4 * 4];  // uniform
            const float* ap = &a_s[h4 * 4 * 32 + ng * 4];
            v2f A0[2], A1[2], A2[2], A3[2];
#pragma unroll
            for (int np = 0; np < 2; ++np) {
                A0[np] = *(const v2f*)&ap[0 * 32 + np * 2];  // broadcasts
                A1[np] = *(const v2f*)&ap[1 * 32 + np * 2];
                A2[np] = *(const v2f*)&ap[2 * 32 + np * 2];
                A3[np] = *(const v2f*)&ap[3 * 32 + np * 2];
            }
#pragma unroll
            for (int mt = 0; mt < 2; ++mt) {
                const float4 b4 = *(const float4*)
                    &b_s[(mt * 64 + lane) * 64 + ((h4 ^ skey) << 2)];
#pragma unroll
                for (int np = 0; np < 2; ++np) {
                    const v2f u0 = A0[np] * b4.x + 1.0f;
                    const v2f u1 = A1[np] * b4.y + 1.0f;
                    const v2f u2 = A2[np] * b4.z + 1.0f;
                    const v2f u3 = A3[np] * b4.w + 1.0f;
                    const v2f p01 = u0 * u1, p23 = u2 * u3;
                    const v2f An = w4.x * u1 + w4.y * u0;
                    const v2f Bn = w4.z * u3 + w4.w * u2;
                    const v2f num = An * p23 + Bn * p01;
                    const v2f Pp = p01 * p23;
                    v2f r2;
                    r2.x = __builtin_amdgcn_rcpf(Pp.x);
                    r2.y = __builtin_amdgcn_rcpf(Pp.y);
                    acc[mt][np] = num * r2 + acc[mt][np];
                }
            }
        }
    }

    const size_t prow = ((size_t)b * NN + n0 + ng * 4) * MM + m0 + lane;
#pragma unroll
    for (int j = 0; j < 4; ++j) {
#pragma unroll
        for (int mt = 0; mt < 2; ++mt) {
            const float pv = __builtin_amdgcn_exp2f(
                fmaf(acc[mt][j >> 1][j & 1], NEG2LOG2E, SHIFT_C));
            Ph[prow + (size_t)j * MM + mt * 64] = __float2half(pv);
            float s = pv;
#pragma unroll
            for (int o = 32; o > 0; o >>= 1) s += __shfl_xor(s, o);
            if (lane == 0)
                psum[((size_t)(m0 / 64 + mt) * BB + b) * NN + n0 + ng * 4 + j] = s;
        }
    }
}

// ---- Kernel 3 v6: full-k LDS-staged MFMA GEMM, normalize fused, direct out.
__global__ __launch_bounds__(512) void attend_kernel(
    const __half* __restrict__ Ph, const __half* __restrict__ KT_hi,
    const float* __restrict__ psum, float* __restrict__ out) {
    __shared__ __align__(16) __half Ab[2][4 * 512];  // 4KB x2
    __shared__ __align__(16) __half Bb[2][8 * 512];  // 8KB x2
    __shared__ float inv[32];

    const int bid = blockIdx.x;
    const int g = bid & 7, nt = bid >> 3;
    const int dt = g >> 1, b = g & 1;
    const int n0 = nt * 32, d0 = dt * 64;

    const int tid = threadIdx.x;
    const int lane = tid & 63;
    const int row16 = lane & 15, kg = lane >> 4;

    if (tid < 32) {
        float s = 0.f;
#pragma unroll
        for (int q = 0; q < 16; ++q)
            s += psum[((size_t)q * BB + b) * NN + n0 + tid];
        inv[tid] = __builtin_amdgcn_rcpf(s);
    }

    const int cb = tid >> 6;
    const int sdB = cb >> 1, skhB = cb & 1;
    const __half* srcB = KT_hi +
        ((size_t)(b * DD + d0 + sdB * 16 + row16)) * MM + skhB * 32 + kg * 8;
    const bool hasA = tid < 256;
    const int ca = cb & 3;
    const int snA = ca >> 1, skhA = ca & 1;
    const __half* srcA = Ph +
        ((size_t)(b * NN + n0 + snA * 16 + row16)) * MM + skhA * 32 + kg * 8;

    const int wave = __builtin_amdgcn_readfirstlane(threadIdx.x >> 6);
    const int t = wave >> 2, td = wave & 3;

    v4f c = {0.f, 0.f, 0.f, 0.f};

    h8 rb = *(const h8*)srcB;
    h8 ra;
    if (hasA) ra = *(const h8*)srcA;

    int cur = 0;
#pragma unroll 1
    for (int step = 0; step < 16; ++step) {
        *(h8*)&Bb[cur][cb * 512 + lane * 8] = rb;
        if (hasA) *(h8*)&Ab[cur][ca * 512 + lane * 8] = ra;
        if (step < 15) {
            rb = *(const h8*)(srcB + (step + 1) * 64);
            if (hasA) ra = *(const h8*)(srcA + (step + 1) * 64);
        }
        asm volatile("s_waitcnt lgkmcnt(0)" ::: "memory");
        __builtin_amdgcn_sched_barrier(0);
        __builtin_amdgcn_s_barrier();  // raw barrier: no vmcnt(0) drain

        const h8 a0 = *(const h8*)&Ab[cur][(t * 2 + 0) * 512 + lane * 8];
        const h8 a1 = *(const h8*)&Ab[cur][(t * 2 + 1) * 512 + lane * 8];
        const h8 b0 = *(const h8*)&Bb[cur][(td * 2 + 0) * 512 + lane * 8];
        const h8 b1 = *(const h8*)&Bb[cur][(td * 2 + 1) * 512 + lane * 8];
        c = __builtin_amdgcn_mfma_f32_16x16x32_f16(a0, b0, c, 0, 0, 0);
        c = __builtin_amdgcn_mfma_f32_16x16x32_f16(a1, b1, c, 0, 0, 0);
        cur ^= 1;
    }

    const int nloc = t * 16 + kg * 4;
    float* po = out + ((size_t)(b * NN + n0 + nloc)) * DD + d0 + td * 16 + row16;
#pragma unroll
    for (int r = 0; r < 4; ++r)
        po[(size_t)r * DD] = c[r] * inv[nloc + r];
}

extern "C" void kernel_launch(void* const* d_in, const int* in_sizes, int n_in,
                              void* d_out, int out_size, void* d_ws, size_t ws_size,
                              hipStream_t stream) {
    const float* query = (const float*)d_in[0];
    const float* key   = (const float*)d_in[1];
    const float* Wa_w  = (const float*)d_in[2];
    const float* Wa_b  = (const float*)d_in[3];
    const float* Wb_w  = (const float*)d_in[4];
    const float* Wb_b  = (const float*)d_in[5];
    const float* v_w   = (const float*)d_in[6];
    float* out = (float*)d_out;

    float* ws = (float*)d_ws;
    float* EaT  = ws;                          // BB*HH*NN f32
    float* Eb   = EaT + BB * NN * HH;          // BB*MM*HH f32
    float* psum = Eb + BB * MM * HH;           // 16*BB*NN f32
    __half* Ph    = (__half*)(psum + 16 * BB * NN);   // BB*NN*MM f16
    __half* KT_hi = Ph + (size_t)BB * NN * MM;        // BB*DD*MM f16

    proj_conv_kernel<<<dim3(512 + 128), dim3(256), 0, stream>>>(
        query, key, Wa_w, Wa_b, Wb_w, Wb_b, EaT, Eb, KT_hi);
    scores_kernel<<<dim3(MM / 128, NN / 32, BB), dim3(512), 0, stream>>>(
        EaT, Eb, v_w, Ph, psum);
    attend_kernel<<<dim3(256), dim3(512), 0, stream>>>(
        Ph, KT_hi, psum, out);
}